// Round 1
// baseline (2014.984 us; speedup 1.0000x reference)
//
#include <hip/hip_runtime.h>
#include <cstdint>
#include <cstddef>

#define Bsz 2048
#define Tseq 60
#define Fin 89
#define Hd 1024
#define G4 4096
#define KX 96
#define NOUT 30

typedef _Float16 half8 __attribute__((ext_vector_type(8)));
typedef float f32x4 __attribute__((ext_vector_type(4)));

__device__ __forceinline__ void gload_lds16(const void* g, void* l) {
  __builtin_amdgcn_global_load_lds((const __attribute__((address_space(1))) void*)g,
                                   (__attribute__((address_space(3))) void*)l,
                                   16, 0, 0);
}

__device__ __forceinline__ float sigmoidf_fast(float x) {
  return 1.0f / (1.0f + __expf(-x));
}

// ---------------------------------------------------------------------------
// Prep kernels (run once per launch; ws is re-poisoned before every call)
// ---------------------------------------------------------------------------

// x [B][T][Fin] fp32 -> xp [T][B][KX] fp16, zero-padded k in [Fin, KX)
__global__ __launch_bounds__(256) void convert_x(const float* __restrict__ x,
                                                 _Float16* __restrict__ xp) {
  int idx = blockIdx.x * 256 + threadIdx.x;   // < Tseq*Bsz*KX
  int k = idx % KX;
  int b = (idx / KX) % Bsz;
  int t = idx / (KX * Bsz);
  float v = (k < Fin) ? x[((size_t)b * Tseq + t) * Fin + k] : 0.0f;
  xp[idx] = (_Float16)v;
}

// W [Fin][G4] fp32 -> Wpt [G4][KX] fp16 (B^T layout, zero rows k>=Fin)
__global__ __launch_bounds__(256) void transpose_W(const float* __restrict__ W,
                                                   _Float16* __restrict__ Wpt) {
  __shared__ float tile[32][33];
  int n0 = blockIdx.x * 32;
  int k0 = blockIdx.y * 32;
  int tx = threadIdx.x, ty = threadIdx.y;
  for (int i = ty; i < 32; i += 8) {
    int k = k0 + i;
    tile[i][tx] = (k < Fin) ? W[(size_t)k * G4 + n0 + tx] : 0.0f;
  }
  __syncthreads();
  for (int i = ty; i < 32; i += 8)
    Wpt[(size_t)(n0 + i) * KX + k0 + tx] = (_Float16)tile[tx][i];
}

// U [Hd][G4] fp32 -> Upt [G4][Hd] fp16 (B^T layout)
__global__ __launch_bounds__(256) void transpose_U(const float* __restrict__ U,
                                                   _Float16* __restrict__ Upt) {
  __shared__ float tile[32][33];
  int n0 = blockIdx.x * 32;
  int k0 = blockIdx.y * 32;
  int tx = threadIdx.x, ty = threadIdx.y;
  for (int i = ty; i < 32; i += 8)
    tile[i][tx] = U[(size_t)(k0 + i) * G4 + n0 + tx];
  __syncthreads();
  for (int i = ty; i < 32; i += 8)
    Upt[(size_t)(n0 + i) * Hd + k0 + tx] = (_Float16)tile[tx][i];
}

__global__ __launch_bounds__(256) void zero_state(float* __restrict__ c,
                                                  _Float16* __restrict__ h0) {
  int i = blockIdx.x * 256 + threadIdx.x;   // < Bsz*Hd
  c[i] = 0.0f;
  h0[i] = (_Float16)0.0f;
}

// ---------------------------------------------------------------------------
// Fused LSTM step: z = x_t@W + h@U + b  (MFMA fp16, fp32 acc), gates in regs.
// Block tile: 128 rows (batch) x [4 gates x 32 hidden units].
// Wave w: rows 64*(w>>1)..+63, hidden units j0 + 16*(w&1)..+15, all 4 gates.
// acc[mi][p] = gate p for the same 16 hidden units -> epilogue is pure-register.
// ---------------------------------------------------------------------------
__global__ __launch_bounds__(256) void lstm_step(
    const _Float16* __restrict__ xp,    // [Tseq][Bsz][KX]
    const _Float16* __restrict__ Wpt,   // [G4][KX]   (B^T)
    const _Float16* __restrict__ Upt,   // [G4][Hd]   (B^T)
    const float*    __restrict__ bias,  // [G4]
    const _Float16* __restrict__ h_in,  // [Bsz][Hd]
    _Float16*       __restrict__ h_out, // [Bsz][Hd]
    float*          __restrict__ cst,   // [Bsz][Hd]
    int t)
{
  __shared__ __align__(16) _Float16 As[128 * 32];  // [row][k]
  __shared__ __align__(16) _Float16 Bs[128 * 32];  // [ln:(gate*32+j)][k]

  const int tid  = threadIdx.x;
  const int wave = tid >> 6;
  const int lane = tid & 63;
  const int quad = lane >> 4;
  const int l16  = lane & 15;
  const int m0 = blockIdx.x * 128;   // batch-row base
  const int j0 = blockIdx.y * 32;    // hidden-unit base

  const int srow  = lane >> 2;        // staging: row within 16-row chunk
  const int skoff = (lane & 3) * 8;   // staging: fp16-element offset in 32-k row

  const int hb    = 16 * (wave & 1);  // hidden sub-base within block
  const int mwave = 64 * (wave >> 1); // row sub-base within block

  // init acc with bias (same bias for all rows; per-gate, per-column)
  f32x4 acc[4][4];
  {
    const int jc = j0 + hb + l16;
    float bv[4];
    for (int p = 0; p < 4; ++p) bv[p] = bias[p * Hd + jc];
    for (int mi = 0; mi < 4; ++mi)
      for (int p = 0; p < 4; ++p)
        acc[mi][p] = f32x4{bv[p], bv[p], bv[p], bv[p]};
  }

  const _Float16* xp_t = xp + (size_t)t * (Bsz * KX);

  for (int kt = 0; kt < 3 + 32; ++kt) {
    const _Float16 *Ab, *Bb;
    int strA, strB, k0;
    if (kt < 3) { Ab = xp_t; strA = KX; Bb = Wpt; strB = KX; k0 = kt * 32; }
    else        { Ab = h_in; strA = Hd; Bb = Upt; strB = Hd; k0 = (kt - 3) * 32; }

    __syncthreads();  // previous tile's ds_reads done before overwrite

    // stage A tile [128][32]: 8 chunks of 16 rows; wave handles chunks w, w+4
    {
      int ci = wave;
      gload_lds16(Ab + (size_t)(m0 + ci * 16 + srow) * strA + k0 + skoff,
                  &As[ci * 512]);
      ci = wave + 4;
      gload_lds16(Ab + (size_t)(m0 + ci * 16 + srow) * strA + k0 + skoff,
                  &As[ci * 512]);
    }
    // stage B tile [128][32]: local row ln -> global row (ln>>5)*Hd + j0 + (ln&31)
    {
      int ci = wave;
      int ln = ci * 16 + srow;
      int gn = (ln >> 5) * Hd + j0 + (ln & 31);
      gload_lds16(Bb + (size_t)gn * strB + k0 + skoff, &Bs[ci * 512]);
      ci = wave + 4;
      ln = ci * 16 + srow;
      gn = (ln >> 5) * Hd + j0 + (ln & 31);
      gload_lds16(Bb + (size_t)gn * strB + k0 + skoff, &Bs[ci * 512]);
    }
    __syncthreads();  // drains vmcnt(0): tiles landed

    half8 a[4], bq[4];
    for (int mi = 0; mi < 4; ++mi)
      a[mi] = *(const half8*)&As[(mwave + mi * 16 + l16) * 32 + quad * 8];
    for (int p = 0; p < 4; ++p)
      bq[p] = *(const half8*)&Bs[(p * 32 + hb + l16) * 32 + quad * 8];
    for (int mi = 0; mi < 4; ++mi)
      for (int p = 0; p < 4; ++p)
        acc[mi][p] = __builtin_amdgcn_mfma_f32_16x16x32_f16(a[mi], bq[p],
                                                            acc[mi][p], 0, 0, 0);
  }

  // epilogue: lane holds i,f,g,o for hidden unit j, rows quad*4+r (C-layout m89)
  const int j = j0 + hb + l16;
  for (int mi = 0; mi < 4; ++mi) {
    for (int r = 0; r < 4; ++r) {
      int row = m0 + mwave + mi * 16 + quad * 4 + r;
      size_t idx = (size_t)row * Hd + j;
      float iv = sigmoidf_fast(acc[mi][0][r]);
      float fv = sigmoidf_fast(acc[mi][1][r]);
      float gv = fmaxf(acc[mi][2][r], 0.0f);   // relu candidate
      float ov = sigmoidf_fast(acc[mi][3][r]);
      float cv = fv * cst[idx] + iv * gv;
      cst[idx] = cv;
      float hv = ov * fmaxf(cv, 0.0f);         // relu on cell output
      h_out[idx] = (_Float16)hv;
    }
  }
}

// ---------------------------------------------------------------------------
// y[b][o] = bd[o] + sum_k h[b][k] * Wd[k][o]
// ---------------------------------------------------------------------------
__global__ __launch_bounds__(256) void final_dense(const _Float16* __restrict__ h,
                                                   const float* __restrict__ Wd,
                                                   const float* __restrict__ bd,
                                                   float* __restrict__ y) {
  __shared__ float hs[Hd];
  __shared__ float red[8][32];
  int bi = blockIdx.x;
  for (int k = threadIdx.x; k < Hd; k += 256)
    hs[k] = (float)h[(size_t)bi * Hd + k];
  __syncthreads();
  int o  = threadIdx.x & 31;
  int ch = threadIdx.x >> 5;
  float p = 0.0f;
  if (o < NOUT) {
    int k0 = ch * (Hd / 8);
    for (int k = k0; k < k0 + (Hd / 8); ++k)
      p += hs[k] * Wd[(size_t)k * NOUT + o];
  }
  red[ch][o] = p;
  __syncthreads();
  if (threadIdx.x < NOUT) {
    float s = bd[threadIdx.x];
    for (int c2 = 0; c2 < 8; ++c2) s += red[c2][threadIdx.x];
    y[(size_t)bi * NOUT + threadIdx.x] = s;
  }
}

// ---------------------------------------------------------------------------

extern "C" void kernel_launch(void* const* d_in, const int* in_sizes, int n_in,
                              void* d_out, int out_size, void* d_ws, size_t ws_size,
                              hipStream_t stream) {
  const float* x  = (const float*)d_in[0];
  const float* W  = (const float*)d_in[1];
  const float* U  = (const float*)d_in[2];
  const float* b  = (const float*)d_in[3];
  const float* Wd = (const float*)d_in[4];
  const float* bd = (const float*)d_in[5];
  float* y = (float*)d_out;

  char* ws = (char*)d_ws;
  _Float16* xp  = (_Float16*)ws; ws += (size_t)Tseq * Bsz * KX * 2;  // 23.6 MB
  _Float16* Wpt = (_Float16*)ws; ws += (size_t)G4 * KX * 2;          // 0.79 MB
  _Float16* Upt = (_Float16*)ws; ws += (size_t)G4 * Hd * 2;          // 8.4 MB
  _Float16* h0  = (_Float16*)ws; ws += (size_t)Bsz * Hd * 2;         // 4.2 MB
  _Float16* h1  = (_Float16*)ws; ws += (size_t)Bsz * Hd * 2;         // 4.2 MB
  float*    cst = (float*)ws;    ws += (size_t)Bsz * Hd * 4;         // 8.4 MB

  convert_x<<<(Tseq * Bsz * KX) / 256, 256, 0, stream>>>(x, xp);
  transpose_W<<<dim3(G4 / 32, KX / 32), dim3(32, 8), 0, stream>>>(W, Wpt);
  transpose_U<<<dim3(G4 / 32, Hd / 32), dim3(32, 8), 0, stream>>>(U, Upt);
  zero_state<<<(Bsz * Hd) / 256, 256, 0, stream>>>(cst, h0);

  _Float16* hin = h0;
  _Float16* hout = h1;
  for (int t = 0; t < Tseq; ++t) {
    lstm_step<<<dim3(Bsz / 128, Hd / 32), 256, 0, stream>>>(
        xp, Wpt, Upt, b, hin, hout, cst, t);
    _Float16* tmp = hin; hin = hout; hout = tmp;
  }
  final_dense<<<Bsz, 256, 0, stream>>>(hin, Wd, bd, y);
}